// Round 15
// baseline (171.438 us; speedup 1.0000x reference)
//
#include <hip/hip_runtime.h>
#include <hip/hip_bf16.h>

typedef __attribute__((ext_vector_type(8))) short short8v;
typedef __attribute__((ext_vector_type(4))) float float4v;
typedef __attribute__((ext_vector_type(4))) unsigned uint4v;

__device__ __forceinline__ unsigned short f2bf(float x) {
    unsigned u = __float_as_uint(x);
    unsigned r = (u + 0x7fffu + ((u >> 16) & 1u)) >> 16;
    return (unsigned short)r;
}
__device__ __forceinline__ float bf2f(unsigned short u) {
    return __uint_as_float((unsigned)u << 16);
}
__device__ __forceinline__ unsigned cvt_pk_bf16(float lo, float hi) {
    unsigned r;
    asm("v_cvt_pk_bf16_f32 %0, %1, %2" : "=v"(r) : "v"(lo), "v"(hi));
    return r;
}
// packed relu on 2 bf16 in a dword: bf16-as-int16 max with 0 == relu (non-NaN)
__device__ __forceinline__ unsigned pk_relu_bf16(unsigned x) {
    unsigned r;
    asm("v_pk_max_i16 %0, %1, %2" : "=v"(r) : "v"(x), "v"(0u));
    return r;
}
// sum across each 16-lane row, result in all lanes (VALU-pipe DPP tree).
__device__ __forceinline__ float dpp_red16(float v) {
    int x = __float_as_int(v);
    v += __int_as_float(__builtin_amdgcn_update_dpp(0, x, 0xB1, 0xF, 0xF, false));
    x = __float_as_int(v);
    v += __int_as_float(__builtin_amdgcn_update_dpp(0, x, 0x4E, 0xF, 0xF, false));
    x = __float_as_int(v);
    v += __int_as_float(__builtin_amdgcn_update_dpp(0, x, 0x124, 0xF, 0xF, false));
    x = __float_as_int(v);
    v += __int_as_float(__builtin_amdgcn_update_dpp(0, x, 0x128, 0xF, 0xF, false));
    return v;
}

// ---------- fused prep: pack2 | packf | corr | w2T | branch128 | branch256 ----------
// grid 2532: [0,112) pack2, [112,436) packf, [436,444) corr, [444,452) w2T,
// [452,2500) branch<128> (a4), [2500,2532) branch<256> (a32).
__global__ __launch_bounds__(256) void k_prep(
    const float* __restrict__ mw0, const float* __restrict__ mw1,
    const float* __restrict__ wf, const float* __restrict__ mb0,
    const float* __restrict__ w2, const float* __restrict__ feats4,
    const float* __restrict__ w4, const float* __restrict__ s4,
    const float* __restrict__ b4, const float* __restrict__ feats32,
    const float* __restrict__ w32, const float* __restrict__ s32,
    const float* __restrict__ b32,
    short* __restrict__ w1p, short* __restrict__ w0fp,
    short* __restrict__ wfp, float* __restrict__ corr,
    float* __restrict__ w2T,
    float* __restrict__ a4buf, float* __restrict__ a32buf) {
    int b = blockIdx.x, t = threadIdx.x;
    if (b < 112) {
        int i = b * 256 + t;                  // 0..28671
        if (i < 16384) {
            int j = i & 7, l = (i >> 3) & 63;
            int nt = (i >> 9) & 7, kt = i >> 12;
            int k = kt * 32 + ((l >> 4) << 3) + j;
            int n = nt * 16 + (l & 15);
            w1p[i] = (short)f2bf(mw1[k * 128 + n]);
        } else {
            int i2 = i - 16384;               // 0..12287
            int j = i2 & 7, l = (i2 >> 3) & 63;
            int nt = (i2 >> 9) & 7, kt = i2 >> 12;
            int k = kt * 32 + ((l >> 4) << 3) + j;
            int n = nt * 16 + (l & 15);
            w0fp[i2] = (short)f2bf(mw0[k * 128 + n]);
        }
    } else if (b < 436) {
        int i = (b - 112) * 256 + t;          // 0..82943
        if (i < 82944) {
            int j = i & 7, l = (i >> 3) & 63;
            int rest = i >> 9;
            int nt = rest % 6, tk = rest / 6;
            int kt = tk % 3, tap = tk / 3;
            int k = kt * 32 + ((l >> 4) << 3) + j;
            int n = nt * 16 + (l & 15);
            wfp[i] = (short)f2bf(wf[((size_t)(tap * 96 + k)) * 96 + n]);
        }
    } else if (b < 444) {
        int i = (b - 436) * 256 + t;          // 0..2047
        int d = i & 127, c = i >> 7;
        float ry = (float)(c >> 2) - 1.5f;
        float rx = (float)(c & 3) - 1.5f;
        corr[i] = fmaf(ry, mw0[96 * 128 + d], fmaf(rx, mw0[97 * 128 + d], mb0[d]));
    } else if (b < 452) {
        int i = (b - 444) * 256 + t;          // 0..2047; w2T[f][c] = w2[c][f]
        int f = i >> 6, c = i & 63;
        w2T[i] = w2[c * 32 + f];
    } else if (b < 2500) {
        int f = t & 31;
        int pi = (b - 452) * 8 + (t >> 5);    // 0..16383
        const float4* xr4 = (const float4*)(feats4 + (size_t)pi * 128);
        float acc = 0.f;
#pragma unroll 8
        for (int c4 = 0; c4 < 32; ++c4) {
            float4 x = xr4[c4];
            acc = fmaf(x.x, w4[(c4 * 4 + 0) * 32 + f], acc);
            acc = fmaf(x.y, w4[(c4 * 4 + 1) * 32 + f], acc);
            acc = fmaf(x.z, w4[(c4 * 4 + 2) * 32 + f], acc);
            acc = fmaf(x.w, w4[(c4 * 4 + 3) * 32 + f], acc);
        }
        float v = fmaf(acc, s4[f], b4[f]);
        a4buf[(size_t)pi * 32 + f] = fmaxf(v, 0.f);
    } else {
        int f = t & 31;
        int pi = (b - 2500) * 8 + (t >> 5);   // 0..255
        const float4* xr4 = (const float4*)(feats32 + (size_t)pi * 256);
        float acc = 0.f;
#pragma unroll 8
        for (int c4 = 0; c4 < 64; ++c4) {
            float4 x = xr4[c4];
            acc = fmaf(x.x, w32[(c4 * 4 + 0) * 32 + f], acc);
            acc = fmaf(x.y, w32[(c4 * 4 + 1) * 32 + f], acc);
            acc = fmaf(x.z, w32[(c4 * 4 + 2) * 32 + f], acc);
            acc = fmaf(x.w, w32[(c4 * 4 + 3) * 32 + f], acc);
        }
        float v = fmaf(acc, s32[f], b32[f]);
        a32buf[(size_t)pi * 32 + f] = fmaxf(v, 0.f);
    }
}

// ---------- cat builder: a2 (1x1 conv, w2T vectorized) + bilinear -> bf16 ----------
__global__ __launch_bounds__(256) void k_cat(
    const float* __restrict__ feats2, const float* __restrict__ w2T,
    const float* __restrict__ s2, const float* __restrict__ b2,
    const float* __restrict__ a4, const float* __restrict__ a32,
    unsigned short* __restrict__ cat) {
    int t = threadIdx.x;
    int f = t & 31;
    int p = blockIdx.x * 8 + (t >> 5);   // 0..65535
    int y = p >> 8, x = p & 255;

    {
        const float4* xr4 = (const float4*)(feats2 + (size_t)p * 64);
        const float4* wt4 = (const float4*)(w2T + f * 64);
        float acc = 0.f;
#pragma unroll
        for (int c4 = 0; c4 < 16; ++c4) {
            float4 xv = xr4[c4];
            float4 wv = wt4[c4];
            acc = fmaf(xv.x, wv.x, acc);
            acc = fmaf(xv.y, wv.y, acc);
            acc = fmaf(xv.z, wv.z, acc);
            acc = fmaf(xv.w, wv.w, acc);
        }
        float v = fmaf(acc, s2[f], b2[f]);
        cat[(size_t)p * 96 + f] = f2bf(fmaxf(v, 0.f));
    }
    {
        float sy = fminf(fmaxf(y * 0.5f - 0.25f, 0.f), 127.f);
        float sx = fminf(fmaxf(x * 0.5f - 0.25f, 0.f), 127.f);
        int y0 = (int)sy; float fy = sy - (float)y0; int y1 = min(y0 + 1, 127);
        int x0 = (int)sx; float fx = sx - (float)x0; int x1 = min(x0 + 1, 127);
        float v00 = a4[((size_t)(y0 * 128 + x0)) * 32 + f];
        float v01 = a4[((size_t)(y0 * 128 + x1)) * 32 + f];
        float v10 = a4[((size_t)(y1 * 128 + x0)) * 32 + f];
        float v11 = a4[((size_t)(y1 * 128 + x1)) * 32 + f];
        float vv = (1.f - fy) * ((1.f - fx) * v00 + fx * v01)
                 + fy * ((1.f - fx) * v10 + fx * v11);
        cat[(size_t)p * 96 + 32 + f] = f2bf(vv);
    }
    {
        float sy = fminf(fmaxf((y + 0.5f) * (1.f / 16.f) - 0.5f, 0.f), 15.f);
        float sx = fminf(fmaxf((x + 0.5f) * (1.f / 16.f) - 0.5f, 0.f), 15.f);
        int y0 = (int)sy; float fy = sy - (float)y0; int y1 = min(y0 + 1, 15);
        int x0 = (int)sx; float fx = sx - (float)x0; int x1 = min(x0 + 1, 15);
        float v00 = a32[((size_t)(y0 * 16 + x0)) * 32 + f];
        float v01 = a32[((size_t)(y0 * 16 + x1)) * 32 + f];
        float v10 = a32[((size_t)(y1 * 16 + x0)) * 32 + f];
        float v11 = a32[((size_t)(y1 * 16 + x1)) * 32 + f];
        float vv = (1.f - fy) * ((1.f - fx) * v00 + fx * v01)
                 + fy * ((1.f - fx) * v10 + fx * v11);
        cat[(size_t)p * 96 + 64 + f] = f2bf(vv);
    }
}

// ---------- 3x3 conv (MFMA) + BN + ReLU -> feat (LDS) -> G = feat @ W0f ----------
// LDS 25.6KB -> 6 blocks/CU if VGPR <= 85 (launch_bounds(256,6)).
__global__ __launch_bounds__(256, 6) void k_fuseG(
    const unsigned short* __restrict__ catb, const short* __restrict__ wfp,
    const float* __restrict__ sf, const float* __restrict__ bfb,
    const short* __restrict__ w0fp, unsigned short* __restrict__ G) {
    __shared__ char Xb[100 * 256];
    int t = threadIdx.x;
    int by = (blockIdx.x >> 5) * 8;
    int bx = (blockIdx.x & 31) * 8;

    if (t < 200) {
        int rp = t >> 1, hf = t & 1;
        int gy = by + rp / 10 - 1;
        int gx = bx + rp % 10 - 1;
        bool ok = (gy >= 0 && gy < 256 && gx >= 0 && gx < 256);
        const unsigned short* src = catb + (size_t)(gy * 256 + gx) * 96 + hf * 48;
        int swz = (rp & 7) << 4;
#pragma unroll
        for (int m = 0; m < 6; ++m) {
            short8v v = {0, 0, 0, 0, 0, 0, 0, 0};
            if (ok) v = *(const short8v*)(src + m * 8);
            *(short8v*)(Xb + rp * 256 + (((hf * 6 + m) * 16) ^ swz)) = v;
        }
    }
    __syncthreads();

    int lane = t & 63, wid = t >> 6;
    int wr = wid >> 1, wc = wid & 1;
    int l15 = lane & 15, g = lane >> 4, kb = g * 16;

    float4v acc[2][3];
#pragma unroll
    for (int rb = 0; rb < 2; ++rb)
#pragma unroll
        for (int n = 0; n < 3; ++n)
            acc[rb][n] = (float4v){0.f, 0.f, 0.f, 0.f};

#pragma unroll
    for (int ky = 0; ky < 3; ++ky) {
#pragma unroll
        for (int kx = 0; kx < 3; ++kx) {
#pragma unroll
            for (int kt = 0; kt < 3; ++kt) {
                const short8v* bp = (const short8v*)wfp
                    + (size_t)((((ky * 3 + kx) * 3 + kt) * 6) + wc * 3) * 64 + lane;
                short8v b0 = bp[0], b1 = bp[64], b2 = bp[128];
#pragma unroll
                for (int rb = 0; rb < 2; ++rb) {
                    int R = wr * 32 + rb * 16 + l15;
                    int rp = ((R >> 3) + ky) * 10 + (R & 7) + kx;
                    short8v a = *(short8v*)(Xb + rp * 256
                                 + ((kt * 64 + kb) ^ ((rp & 7) << 4)));
                    acc[rb][0] = __builtin_amdgcn_mfma_f32_16x16x32_bf16(a, b0, acc[rb][0], 0, 0, 0);
                    acc[rb][1] = __builtin_amdgcn_mfma_f32_16x16x32_bf16(a, b1, acc[rb][1], 0, 0, 0);
                    acc[rb][2] = __builtin_amdgcn_mfma_f32_16x16x32_bf16(a, b2, acc[rb][2], 0, 0, 0);
                }
            }
        }
    }
    __syncthreads();   // conv LDS reads done; Xb reusable

    // feat (bf16, BN+ReLU applied) -> Xb as [64 rows][96 ch], pitch 256, swizzled
#pragma unroll
    for (int rb = 0; rb < 2; ++rb) {
#pragma unroll
        for (int n = 0; n < 3; ++n) {
            int ch = (wc * 3 + n) * 16 + l15;
            float sc = sf[ch], bi = bfb[ch];
#pragma unroll
            for (int j = 0; j < 4; ++j) {
                int R = wr * 32 + rb * 16 + g * 4 + j;
                *(short*)(Xb + R * 256 + ((ch * 2) ^ ((R & 7) << 4))) =
                    (short)f2bf(fmaxf(fmaf(acc[rb][n][j], sc, bi), 0.f));
            }
        }
    }
    __syncthreads();

    // G-stage: 64 rows x 128 cols, K=96. Wave wid owns cols [32*wid, 32*wid+32).
    float4v a2[4][2];
#pragma unroll
    for (int r = 0; r < 4; ++r)
#pragma unroll
        for (int n = 0; n < 2; ++n)
            a2[r][n] = (float4v){0.f, 0.f, 0.f, 0.f};

#pragma unroll
    for (int kt = 0; kt < 3; ++kt) {
        const short8v* bp = (const short8v*)w0fp + (kt * 8 + wid * 2) * 64 + lane;
        short8v b0 = bp[0], b1 = bp[64];
#pragma unroll
        for (int r = 0; r < 4; ++r) {
            int row = r * 16 + l15;
            short8v a = *(short8v*)(Xb + row * 256 + ((kt * 64 + kb) ^ ((row & 7) << 4)));
            a2[r][0] = __builtin_amdgcn_mfma_f32_16x16x32_bf16(a, b0, a2[r][0], 0, 0, 0);
            a2[r][1] = __builtin_amdgcn_mfma_f32_16x16x32_bf16(a, b1, a2[r][1], 0, 0, 0);
        }
    }

#pragma unroll
    for (int r = 0; r < 4; ++r) {
#pragma unroll
        for (int n = 0; n < 2; ++n) {
            int colg = (wid * 2 + n) * 16 + l15;
#pragma unroll
            for (int j = 0; j < 4; ++j) {
                int R = r * 16 + g * 4 + j;
                int pix = (by + (R >> 3)) * 256 + bx + (R & 7);
                G[(size_t)pix * 128 + colg] = f2bf(a2[r][n][j]);
            }
        }
    }
}

// ---------- per-cell MLP: dense GEMM over (cell, case), u32-packed A-build ----------
__global__ __launch_bounds__(512) void k_mlpC(
    const unsigned short* __restrict__ G,
    const float* __restrict__ corr,
    const short* __restrict__ w1p, const float* __restrict__ b1g,
    const float* __restrict__ w2g,
    float* __restrict__ pred) {
    __shared__ short8v Bs[2048];          // 32KB packed W1
    __shared__ float cT[2][4][64][4];     // corrT: [half][kt][lane][j] (8KB)
    __shared__ float b1s[128], w2s[128];
    int t = threadIdx.x;
    int lane = t & 63, wid = t >> 6;      // wid 0..7
    int l15 = lane & 15, g = lane >> 4;

    {
        const short8v* wp = (const short8v*)w1p;
#pragma unroll
        for (int i = 0; i < 4; ++i)
            Bs[t + i * 512] = wp[t + i * 512];
#pragma unroll
        for (int r = 0; r < 4; ++r) {
            int idx = t + r * 512;                    // 0..2047
            int j = idx & 3, ln = (idx >> 2) & 63;
            int kt = (idx >> 8) & 3, h = idx >> 10;
            cT[h][kt][ln][j] =
                corr[(ln & 15) * 128 + kt * 32 + ((ln >> 4) << 3) + h * 4 + j];
        }
        if (t < 128) b1s[t] = b1g[t];
        else if (t < 256) w2s[t - 128] = w2g[t - 128];
    }
    __syncthreads();

    int cell0 = (blockIdx.x & 7) * 8192 + (blockIdx.x >> 3) * 32 + wid * 4;
    const unsigned* gbase = (const unsigned*)G + (size_t)cell0 * 64 + g * 4;

#pragma unroll
    for (int s = 0; s < 2; ++s) {
        const unsigned* gA = gbase + s * 128;       // cell ca
        const unsigned* gB = gA + 64;               // cell cb

        short8v afA[4], afB[4];
#pragma unroll
        for (int kt = 0; kt < 4; ++kt) {
            uint4v wa = *(const uint4v*)(gA + kt * 16);
            uint4v wb = *(const uint4v*)(gB + kt * 16);
            float4 c0 = *(const float4*)&cT[0][kt][lane][0];
            float4 c1 = *(const float4*)&cT[1][kt][lane][0];
            uint4v ua, ub;
            {
                unsigned w = wa[0];
                ua[0] = pk_relu_bf16(cvt_pk_bf16(
                    __uint_as_float(w << 16) + c0.x,
                    __uint_as_float(w & 0xFFFF0000u) + c0.y));
                w = wa[1];
                ua[1] = pk_relu_bf16(cvt_pk_bf16(
                    __uint_as_float(w << 16) + c0.z,
                    __uint_as_float(w & 0xFFFF0000u) + c0.w));
                w = wa[2];
                ua[2] = pk_relu_bf16(cvt_pk_bf16(
                    __uint_as_float(w << 16) + c1.x,
                    __uint_as_float(w & 0xFFFF0000u) + c1.y));
                w = wa[3];
                ua[3] = pk_relu_bf16(cvt_pk_bf16(
                    __uint_as_float(w << 16) + c1.z,
                    __uint_as_float(w & 0xFFFF0000u) + c1.w));
            }
            {
                unsigned w = wb[0];
                ub[0] = pk_relu_bf16(cvt_pk_bf16(
                    __uint_as_float(w << 16) + c0.x,
                    __uint_as_float(w & 0xFFFF0000u) + c0.y));
                w = wb[1];
                ub[1] = pk_relu_bf16(cvt_pk_bf16(
                    __uint_as_float(w << 16) + c0.z,
                    __uint_as_float(w & 0xFFFF0000u) + c0.w));
                w = wb[2];
                ub[2] = pk_relu_bf16(cvt_pk_bf16(
                    __uint_as_float(w << 16) + c1.x,
                    __uint_as_float(w & 0xFFFF0000u) + c1.y));
                w = wb[3];
                ub[3] = pk_relu_bf16(cvt_pk_bf16(
                    __uint_as_float(w << 16) + c1.z,
                    __uint_as_float(w & 0xFFFF0000u) + c1.w));
            }
            afA[kt] = __builtin_bit_cast(short8v, ua);
            afB[kt] = __builtin_bit_cast(short8v, ub);
        }

        float part[2][4];
#pragma unroll
        for (int c = 0; c < 2; ++c)
#pragma unroll
            for (int j = 0; j < 4; ++j) part[c][j] = 0.f;

#pragma unroll
        for (int nh = 0; nh < 2; ++nh) {
            float4v accA[4], accB[4];
            float wv[4];
#pragma unroll
            for (int n = 0; n < 4; ++n) {
                int colg = (nh * 4 + n) * 16 + l15;
                float bv = b1s[colg];
                wv[n] = w2s[colg];
                accA[n] = (float4v){bv, bv, bv, bv};
                accB[n] = (float4v){bv, bv, bv, bv};
            }
            __builtin_amdgcn_s_setprio(1);
#pragma unroll
            for (int kt = 0; kt < 4; ++kt) {
#pragma unroll
                for (int n = 0; n < 4; ++n) {
                    short8v b = Bs[(kt * 8 + nh * 4 + n) * 64 + lane];
                    accA[n] = __builtin_amdgcn_mfma_f32_16x16x32_bf16(afA[kt], b, accA[n], 0, 0, 0);
                    accB[n] = __builtin_amdgcn_mfma_f32_16x16x32_bf16(afB[kt], b, accB[n], 0, 0, 0);
                }
            }
            __builtin_amdgcn_s_setprio(0);
#pragma unroll
            for (int n = 0; n < 4; ++n)
#pragma unroll
                for (int j = 0; j < 4; ++j) {
                    part[0][j] += fmaxf(accA[n][j], 0.f) * wv[n];
                    part[1][j] += fmaxf(accB[n][j], 0.f) * wv[n];
                }
        }

#pragma unroll
        for (int c = 0; c < 2; ++c)
#pragma unroll
            for (int j = 0; j < 4; ++j)
                part[c][j] = dpp_red16(part[c][j]);

        if (l15 == 0) {
            int ca = cell0 + s * 2;
            float4 pa = make_float4(part[0][0], part[0][1], part[0][2], part[0][3]);
            float4 pb = make_float4(part[1][0], part[1][1], part[1][2], part[1][3]);
            *(float4*)(pred + (size_t)ca * 16 + g * 4) = pa;
            *(float4*)(pred + (size_t)(ca + 1) * 16 + g * 4) = pb;
        }
    }
}

// ---------- ensemble pass: per pixel gather 4 preds + areas + combine ----------
__global__ __launch_bounds__(256) void k_ens(
    const float* __restrict__ pred, const float* __restrict__ b2g,
    float* __restrict__ out) {
    int p = blockIdx.x * 256 + threadIdx.x;   // 0..262143
    int qy = p >> 9, qx = p & 511;
    float bb = b2g[0];
    float pr[4], ar[4];
#pragma unroll
    for (int br = 0; br < 4; ++br) {
        int iy = min(max((qy + ((br & 2) ? 1 : -1)) >> 1, 0), 255);
        int ix = min(max((qx + ((br & 1) ? 1 : -1)) >> 1, 0), 255);
        int cy = qy - 2 * iy + 1, cx = qx - 2 * ix + 1;
        pr[br] = pred[((size_t)(iy * 256 + ix) * 16) + cy * 4 + cx] + bb;
        float ry = (float)(qy - 2 * iy) - 0.5f;
        float rx = (float)(qx - 2 * ix) - 0.5f;
        ar[br] = fabsf(ry * rx) + 1e-9f;
    }
    out[p] = (pr[0] * ar[3] + pr[1] * ar[2] + pr[2] * ar[1] + pr[3] * ar[0])
           / (ar[0] + ar[1] + ar[2] + ar[3]);
}

// ---------- host launcher ----------
extern "C" void kernel_launch(void* const* d_in, const int* in_sizes, int n_in,
                              void* d_out, int out_size, void* d_ws, size_t ws_size,
                              hipStream_t stream) {
    const float* feats2 = (const float*)d_in[0];
    const float* feats4 = (const float*)d_in[1];
    const float* feats32 = (const float*)d_in[2];
    const float* w2 = (const float*)d_in[4];
    const float* s2 = (const float*)d_in[5];
    const float* b2 = (const float*)d_in[6];
    const float* w4 = (const float*)d_in[7];
    const float* s4 = (const float*)d_in[8];
    const float* b4 = (const float*)d_in[9];
    const float* w32 = (const float*)d_in[10];
    const float* s32 = (const float*)d_in[11];
    const float* b32 = (const float*)d_in[12];
    const float* wf = (const float*)d_in[13];
    const float* sf = (const float*)d_in[14];
    const float* bf = (const float*)d_in[15];
    const float* mw0 = (const float*)d_in[16];
    const float* mb0 = (const float*)d_in[17];
    const float* mw1 = (const float*)d_in[18];
    const float* mb1 = (const float*)d_in[19];
    const float* mw2 = (const float*)d_in[20];
    const float* mb2 = (const float*)d_in[21];

    float* a4buf = (float*)d_ws;                          // 128*128*32 f32
    float* a32buf = a4buf + 524288;                       // 16*16*32 f32
    unsigned short* catb16 = (unsigned short*)(a32buf + 8192);   // 65536*96 bf16
    unsigned short* Gbuf = catb16 + 6291456;                     // 65536*128 bf16
    short* w1p = (short*)(Gbuf + 8388608);                // 16384 bf16
    short* w0fp = w1p + 16384;                            // 12288 bf16
    short* wfp = w0fp + 12288;                            // 82944 bf16
    float* corrbuf = (float*)(wfp + 82944);               // 16*128 f32
    float* predbuf = corrbuf + 2048;                      // 65536*16 f32 (4MB)
    float* w2Tbuf = predbuf + 1048576;                    // 32*64 f32

    k_prep<<<2532, 256, 0, stream>>>(mw0, mw1, wf, mb0, w2,
                                     feats4, w4, s4, b4,
                                     feats32, w32, s32, b32,
                                     w1p, w0fp, wfp, corrbuf, w2Tbuf,
                                     a4buf, a32buf);
    k_cat<<<8192, 256, 0, stream>>>(feats2, w2Tbuf, s2, b2, a4buf, a32buf, catb16);
    k_fuseG<<<1024, 256, 0, stream>>>(catb16, wfp, sf, bf, w0fp, Gbuf);
    k_mlpC<<<2048, 512, 0, stream>>>(Gbuf, corrbuf, w1p, mb1, mw2, predbuf);
    k_ens<<<1024, 256, 0, stream>>>(predbuf, mb2, (float*)d_out);
}

// Round 16
// 99.581 us; speedup vs baseline: 1.7216x; 1.7216x over previous
//
#include <hip/hip_runtime.h>
#include <hip/hip_bf16.h>

typedef __attribute__((ext_vector_type(8))) short short8v;
typedef __attribute__((ext_vector_type(4))) float float4v;
typedef __attribute__((ext_vector_type(4))) unsigned uint4v;

__device__ __forceinline__ unsigned short f2bf(float x) {
    unsigned u = __float_as_uint(x);
    unsigned r = (u + 0x7fffu + ((u >> 16) & 1u)) >> 16;
    return (unsigned short)r;
}
__device__ __forceinline__ float bf2f(unsigned short u) {
    return __uint_as_float((unsigned)u << 16);
}
__device__ __forceinline__ unsigned cvt_pk_bf16(float lo, float hi) {
    unsigned r;
    asm("v_cvt_pk_bf16_f32 %0, %1, %2" : "=v"(r) : "v"(lo), "v"(hi));
    return r;
}
// packed relu on 2 bf16 in a dword: bf16-as-int16 max with 0 == relu (non-NaN)
__device__ __forceinline__ unsigned pk_relu_bf16(unsigned x) {
    unsigned r;
    asm("v_pk_max_i16 %0, %1, %2" : "=v"(r) : "v"(x), "v"(0u));
    return r;
}
// sum across each 16-lane row, result in all lanes (VALU-pipe DPP tree).
__device__ __forceinline__ float dpp_red16(float v) {
    int x = __float_as_int(v);
    v += __int_as_float(__builtin_amdgcn_update_dpp(0, x, 0xB1, 0xF, 0xF, false));
    x = __float_as_int(v);
    v += __int_as_float(__builtin_amdgcn_update_dpp(0, x, 0x4E, 0xF, 0xF, false));
    x = __float_as_int(v);
    v += __int_as_float(__builtin_amdgcn_update_dpp(0, x, 0x124, 0xF, 0xF, false));
    x = __float_as_int(v);
    v += __int_as_float(__builtin_amdgcn_update_dpp(0, x, 0x128, 0xF, 0xF, false));
    return v;
}

// ---------- fused prep: pack2 | packf | corr | w2fp | branch128 | branch256 ----------
// grid 2532: [0,112) pack2, [112,436) packf, [436,444) corr, [444,452) w2fp,
// [452,2500) branch<128> (a4), [2500,2532) branch<256> (a32).
__global__ __launch_bounds__(256) void k_prep(
    const float* __restrict__ mw0, const float* __restrict__ mw1,
    const float* __restrict__ wf, const float* __restrict__ mb0,
    const float* __restrict__ w2, const float* __restrict__ feats4,
    const float* __restrict__ w4, const float* __restrict__ s4,
    const float* __restrict__ b4, const float* __restrict__ feats32,
    const float* __restrict__ w32, const float* __restrict__ s32,
    const float* __restrict__ b32,
    short* __restrict__ w1p, short* __restrict__ w0fp,
    short* __restrict__ wfp, float* __restrict__ corr,
    short* __restrict__ w2fp,
    float* __restrict__ a4buf, float* __restrict__ a32buf) {
    int b = blockIdx.x, t = threadIdx.x;
    if (b < 112) {
        int i = b * 256 + t;                  // 0..28671
        if (i < 16384) {
            int j = i & 7, l = (i >> 3) & 63;
            int nt = (i >> 9) & 7, kt = i >> 12;
            int k = kt * 32 + ((l >> 4) << 3) + j;
            int n = nt * 16 + (l & 15);
            w1p[i] = (short)f2bf(mw1[k * 128 + n]);
        } else {
            int i2 = i - 16384;               // 0..12287
            int j = i2 & 7, l = (i2 >> 3) & 63;
            int nt = (i2 >> 9) & 7, kt = i2 >> 12;
            int k = kt * 32 + ((l >> 4) << 3) + j;
            int n = nt * 16 + (l & 15);
            w0fp[i2] = (short)f2bf(mw0[k * 128 + n]);
        }
    } else if (b < 436) {
        int i = (b - 112) * 256 + t;          // 0..82943
        if (i < 82944) {
            int j = i & 7, l = (i >> 3) & 63;
            int rest = i >> 9;
            int nt = rest % 6, tk = rest / 6;
            int kt = tk % 3, tap = tk / 3;
            int k = kt * 32 + ((l >> 4) << 3) + j;
            int n = nt * 16 + (l & 15);
            wfp[i] = (short)f2bf(wf[((size_t)(tap * 96 + k)) * 96 + n]);
        }
    } else if (b < 444) {
        int i = (b - 436) * 256 + t;          // 0..2047
        int d = i & 127, c = i >> 7;
        float ry = (float)(c >> 2) - 1.5f;
        float rx = (float)(c & 3) - 1.5f;
        corr[i] = fmaf(ry, mw0[96 * 128 + d], fmaf(rx, mw0[97 * 128 + d], mb0[d]));
    } else if (b < 452) {
        int i = (b - 444) * 256 + t;          // 0..2047
        int j = i & 7, l = (i >> 3) & 63;
        int nt = (i >> 9) & 1, kt = (i >> 10) & 1;
        int k = kt * 32 + ((l >> 4) << 3) + j;    // 0..63
        int n = nt * 16 + (l & 15);               // 0..31
        w2fp[i] = (short)f2bf(w2[k * 32 + n]);
    } else if (b < 2500) {
        int f = t & 31;
        int pi = (b - 452) * 8 + (t >> 5);    // 0..16383
        const float4* xr4 = (const float4*)(feats4 + (size_t)pi * 128);
        float acc = 0.f;
#pragma unroll 8
        for (int c4 = 0; c4 < 32; ++c4) {
            float4 x = xr4[c4];
            acc = fmaf(x.x, w4[(c4 * 4 + 0) * 32 + f], acc);
            acc = fmaf(x.y, w4[(c4 * 4 + 1) * 32 + f], acc);
            acc = fmaf(x.z, w4[(c4 * 4 + 2) * 32 + f], acc);
            acc = fmaf(x.w, w4[(c4 * 4 + 3) * 32 + f], acc);
        }
        float v = fmaf(acc, s4[f], b4[f]);
        a4buf[(size_t)pi * 32 + f] = fmaxf(v, 0.f);
    } else {
        int f = t & 31;
        int pi = (b - 2500) * 8 + (t >> 5);   // 0..255
        const float4* xr4 = (const float4*)(feats32 + (size_t)pi * 256);
        float acc = 0.f;
#pragma unroll 8
        for (int c4 = 0; c4 < 64; ++c4) {
            float4 x = xr4[c4];
            acc = fmaf(x.x, w32[(c4 * 4 + 0) * 32 + f], acc);
            acc = fmaf(x.y, w32[(c4 * 4 + 1) * 32 + f], acc);
            acc = fmaf(x.z, w32[(c4 * 4 + 2) * 32 + f], acc);
            acc = fmaf(x.w, w32[(c4 * 4 + 3) * 32 + f], acc);
        }
        float v = fmaf(acc, s32[f], b32[f]);
        a32buf[(size_t)pi * 32 + f] = fmaxf(v, 0.f);
    }
}

// ---------- cat builder v2: a2 via bf16 MFMA + f32 bilinear -> bf16 ----------
// 1024 blocks x 256 thr, 64 px/block. A-tile: 64px x 64ch bf16 in LDS (8KB,
// XOR-swizzled). B = w2fp fragments from L1. Bilinear unchanged (f32 exact).
__global__ __launch_bounds__(256) void k_cat2(
    const float* __restrict__ feats2, const short* __restrict__ w2fp,
    const float* __restrict__ s2, const float* __restrict__ b2,
    const float* __restrict__ a4, const float* __restrict__ a32,
    unsigned short* __restrict__ cat) {
    __shared__ char As[64 * 128];
    int t = threadIdx.x;
    int p0 = blockIdx.x * 64;

    // stage feats2 tile -> bf16 LDS (coalesced float4 reads)
    {
        int r = t >> 2, q = t & 3;
        const float4* src = (const float4*)(feats2 + (size_t)(p0 + r) * 64 + q * 16);
        unsigned u[8];
#pragma unroll
        for (int m = 0; m < 4; ++m) {
            float4 x = src[m];
            u[m * 2 + 0] = cvt_pk_bf16(x.x, x.y);
            u[m * 2 + 1] = cvt_pk_bf16(x.z, x.w);
        }
        int sw = (r & 7) << 4;
        *(uint4v*)(As + r * 128 + ((q * 32) ^ sw)) = (uint4v){u[0], u[1], u[2], u[3]};
        *(uint4v*)(As + r * 128 + ((q * 32 + 16) ^ sw)) = (uint4v){u[4], u[5], u[6], u[7]};
    }
    __syncthreads();

    int lane = t & 63, wid = t >> 6;
    int l15 = lane & 15, g = lane >> 4;

    // a2 conv: wave wid -> 16 px, 2x2 MFMA (kt x nt)
    {
        int row = wid * 16 + l15;
        int sw = (row & 7) << 4;
        float4v acc[2];
#pragma unroll
        for (int nt = 0; nt < 2; ++nt) acc[nt] = (float4v){0.f, 0.f, 0.f, 0.f};
#pragma unroll
        for (int kt = 0; kt < 2; ++kt) {
            short8v a = *(short8v*)(As + row * 128 + ((kt * 64 + g * 16) ^ sw));
#pragma unroll
            for (int nt = 0; nt < 2; ++nt) {
                short8v bfr = *((const short8v*)w2fp + (kt * 2 + nt) * 64 + lane);
                acc[nt] = __builtin_amdgcn_mfma_f32_16x16x32_bf16(a, bfr, acc[nt], 0, 0, 0);
            }
        }
#pragma unroll
        for (int nt = 0; nt < 2; ++nt) {
            int f = nt * 16 + l15;
            float sc = s2[f], bi = b2[f];
#pragma unroll
            for (int j = 0; j < 4; ++j) {
                int px = p0 + wid * 16 + g * 4 + j;
                cat[(size_t)px * 96 + f] = f2bf(fmaxf(fmaf(acc[nt][j], sc, bi), 0.f));
            }
        }
    }

    // bilinear a4 / a32 (f32 exact, coalesced across f)
    int f = t & 31;
#pragma unroll
    for (int pi = 0; pi < 8; ++pi) {
        int p = p0 + pi * 8 + (t >> 5);
        int y = p >> 8, x = p & 255;
        {
            float sy = fminf(fmaxf(y * 0.5f - 0.25f, 0.f), 127.f);
            float sx = fminf(fmaxf(x * 0.5f - 0.25f, 0.f), 127.f);
            int y0 = (int)sy; float fy = sy - (float)y0; int y1 = min(y0 + 1, 127);
            int x0 = (int)sx; float fx = sx - (float)x0; int x1 = min(x0 + 1, 127);
            float v00 = a4[((size_t)(y0 * 128 + x0)) * 32 + f];
            float v01 = a4[((size_t)(y0 * 128 + x1)) * 32 + f];
            float v10 = a4[((size_t)(y1 * 128 + x0)) * 32 + f];
            float v11 = a4[((size_t)(y1 * 128 + x1)) * 32 + f];
            float vv = (1.f - fy) * ((1.f - fx) * v00 + fx * v01)
                     + fy * ((1.f - fx) * v10 + fx * v11);
            cat[(size_t)p * 96 + 32 + f] = f2bf(vv);
        }
        {
            float sy = fminf(fmaxf((y + 0.5f) * (1.f / 16.f) - 0.5f, 0.f), 15.f);
            float sx = fminf(fmaxf((x + 0.5f) * (1.f / 16.f) - 0.5f, 0.f), 15.f);
            int y0 = (int)sy; float fy = sy - (float)y0; int y1 = min(y0 + 1, 15);
            int x0 = (int)sx; float fx = sx - (float)x0; int x1 = min(x0 + 1, 15);
            float v00 = a32[((size_t)(y0 * 16 + x0)) * 32 + f];
            float v01 = a32[((size_t)(y0 * 16 + x1)) * 32 + f];
            float v10 = a32[((size_t)(y1 * 16 + x0)) * 32 + f];
            float v11 = a32[((size_t)(y1 * 16 + x1)) * 32 + f];
            float vv = (1.f - fy) * ((1.f - fx) * v00 + fx * v01)
                     + fy * ((1.f - fx) * v10 + fx * v11);
            cat[(size_t)p * 96 + 64 + f] = f2bf(vv);
        }
    }
}

// ---------- 3x3 conv (MFMA) + BN + ReLU -> feat (LDS) -> G = feat @ W0f ----------
__global__ __launch_bounds__(256, 4) void k_fuseG(
    const unsigned short* __restrict__ catb, const short* __restrict__ wfp,
    const float* __restrict__ sf, const float* __restrict__ bfb,
    const short* __restrict__ w0fp, unsigned short* __restrict__ G) {
    __shared__ char Xb[100 * 256];
    int t = threadIdx.x;
    int by = (blockIdx.x >> 5) * 8;
    int bx = (blockIdx.x & 31) * 8;

    if (t < 200) {
        int rp = t >> 1, hf = t & 1;
        int gy = by + rp / 10 - 1;
        int gx = bx + rp % 10 - 1;
        bool ok = (gy >= 0 && gy < 256 && gx >= 0 && gx < 256);
        const unsigned short* src = catb + (size_t)(gy * 256 + gx) * 96 + hf * 48;
        int swz = (rp & 7) << 4;
#pragma unroll
        for (int m = 0; m < 6; ++m) {
            short8v v = {0, 0, 0, 0, 0, 0, 0, 0};
            if (ok) v = *(const short8v*)(src + m * 8);
            *(short8v*)(Xb + rp * 256 + (((hf * 6 + m) * 16) ^ swz)) = v;
        }
    }
    __syncthreads();

    int lane = t & 63, wid = t >> 6;
    int wr = wid >> 1, wc = wid & 1;
    int l15 = lane & 15, g = lane >> 4, kb = g * 16;

    float4v acc[2][3];
#pragma unroll
    for (int rb = 0; rb < 2; ++rb)
#pragma unroll
        for (int n = 0; n < 3; ++n)
            acc[rb][n] = (float4v){0.f, 0.f, 0.f, 0.f};

#pragma unroll
    for (int ky = 0; ky < 3; ++ky) {
#pragma unroll
        for (int kx = 0; kx < 3; ++kx) {
#pragma unroll
            for (int kt = 0; kt < 3; ++kt) {
                const short8v* bp = (const short8v*)wfp
                    + (size_t)((((ky * 3 + kx) * 3 + kt) * 6) + wc * 3) * 64 + lane;
                short8v b0 = bp[0], b1 = bp[64], b2 = bp[128];
#pragma unroll
                for (int rb = 0; rb < 2; ++rb) {
                    int R = wr * 32 + rb * 16 + l15;
                    int rp = ((R >> 3) + ky) * 10 + (R & 7) + kx;
                    short8v a = *(short8v*)(Xb + rp * 256
                                 + ((kt * 64 + kb) ^ ((rp & 7) << 4)));
                    acc[rb][0] = __builtin_amdgcn_mfma_f32_16x16x32_bf16(a, b0, acc[rb][0], 0, 0, 0);
                    acc[rb][1] = __builtin_amdgcn_mfma_f32_16x16x32_bf16(a, b1, acc[rb][1], 0, 0, 0);
                    acc[rb][2] = __builtin_amdgcn_mfma_f32_16x16x32_bf16(a, b2, acc[rb][2], 0, 0, 0);
                }
            }
        }
    }
    __syncthreads();   // conv LDS reads done; Xb reusable

    // feat (bf16, BN+ReLU applied) -> Xb as [64 rows][96 ch], pitch 256, swizzled
#pragma unroll
    for (int rb = 0; rb < 2; ++rb) {
#pragma unroll
        for (int n = 0; n < 3; ++n) {
            int ch = (wc * 3 + n) * 16 + l15;
            float sc = sf[ch], bi = bfb[ch];
#pragma unroll
            for (int j = 0; j < 4; ++j) {
                int R = wr * 32 + rb * 16 + g * 4 + j;
                *(short*)(Xb + R * 256 + ((ch * 2) ^ ((R & 7) << 4))) =
                    (short)f2bf(fmaxf(fmaf(acc[rb][n][j], sc, bi), 0.f));
            }
        }
    }
    __syncthreads();

    // G-stage: 64 rows x 128 cols, K=96. Wave wid owns cols [32*wid, 32*wid+32).
    float4v a2[4][2];
#pragma unroll
    for (int r = 0; r < 4; ++r)
#pragma unroll
        for (int n = 0; n < 2; ++n)
            a2[r][n] = (float4v){0.f, 0.f, 0.f, 0.f};

#pragma unroll
    for (int kt = 0; kt < 3; ++kt) {
        const short8v* bp = (const short8v*)w0fp + (kt * 8 + wid * 2) * 64 + lane;
        short8v b0 = bp[0], b1 = bp[64];
#pragma unroll
        for (int r = 0; r < 4; ++r) {
            int row = r * 16 + l15;
            short8v a = *(short8v*)(Xb + row * 256 + ((kt * 64 + kb) ^ ((row & 7) << 4)));
            a2[r][0] = __builtin_amdgcn_mfma_f32_16x16x32_bf16(a, b0, a2[r][0], 0, 0, 0);
            a2[r][1] = __builtin_amdgcn_mfma_f32_16x16x32_bf16(a, b1, a2[r][1], 0, 0, 0);
        }
    }

#pragma unroll
    for (int r = 0; r < 4; ++r) {
#pragma unroll
        for (int n = 0; n < 2; ++n) {
            int colg = (wid * 2 + n) * 16 + l15;
#pragma unroll
            for (int j = 0; j < 4; ++j) {
                int R = r * 16 + g * 4 + j;
                int pix = (by + (R >> 3)) * 256 + bx + (R & 7);
                G[(size_t)pix * 128 + colg] = f2bf(a2[r][n][j]);
            }
        }
    }
}

// ---------- per-cell MLP: dense GEMM over (cell, case), u32-packed A-build ----------
__global__ __launch_bounds__(512) void k_mlpC(
    const unsigned short* __restrict__ G,
    const float* __restrict__ corr,
    const short* __restrict__ w1p, const float* __restrict__ b1g,
    const float* __restrict__ w2g,
    float* __restrict__ pred) {
    __shared__ short8v Bs[2048];          // 32KB packed W1
    __shared__ float cT[2][4][64][4];     // corrT: [half][kt][lane][j] (8KB)
    __shared__ float b1s[128], w2s[128];
    int t = threadIdx.x;
    int lane = t & 63, wid = t >> 6;      // wid 0..7
    int l15 = lane & 15, g = lane >> 4;

    {
        const short8v* wp = (const short8v*)w1p;
#pragma unroll
        for (int i = 0; i < 4; ++i)
            Bs[t + i * 512] = wp[t + i * 512];
#pragma unroll
        for (int r = 0; r < 4; ++r) {
            int idx = t + r * 512;                    // 0..2047
            int j = idx & 3, ln = (idx >> 2) & 63;
            int kt = (idx >> 8) & 3, h = idx >> 10;
            cT[h][kt][ln][j] =
                corr[(ln & 15) * 128 + kt * 32 + ((ln >> 4) << 3) + h * 4 + j];
        }
        if (t < 128) b1s[t] = b1g[t];
        else if (t < 256) w2s[t - 128] = w2g[t - 128];
    }
    __syncthreads();

    int cell0 = (blockIdx.x & 7) * 8192 + (blockIdx.x >> 3) * 32 + wid * 4;
    const unsigned* gbase = (const unsigned*)G + (size_t)cell0 * 64 + g * 4;

#pragma unroll
    for (int s = 0; s < 2; ++s) {
        const unsigned* gA = gbase + s * 128;       // cell ca
        const unsigned* gB = gA + 64;               // cell cb

        short8v afA[4], afB[4];
#pragma unroll
        for (int kt = 0; kt < 4; ++kt) {
            uint4v wa = *(const uint4v*)(gA + kt * 16);
            uint4v wb = *(const uint4v*)(gB + kt * 16);
            float4 c0 = *(const float4*)&cT[0][kt][lane][0];
            float4 c1 = *(const float4*)&cT[1][kt][lane][0];
            uint4v ua, ub;
            {
                unsigned w = wa[0];
                ua[0] = pk_relu_bf16(cvt_pk_bf16(
                    __uint_as_float(w << 16) + c0.x,
                    __uint_as_float(w & 0xFFFF0000u) + c0.y));
                w = wa[1];
                ua[1] = pk_relu_bf16(cvt_pk_bf16(
                    __uint_as_float(w << 16) + c0.z,
                    __uint_as_float(w & 0xFFFF0000u) + c0.w));
                w = wa[2];
                ua[2] = pk_relu_bf16(cvt_pk_bf16(
                    __uint_as_float(w << 16) + c1.x,
                    __uint_as_float(w & 0xFFFF0000u) + c1.y));
                w = wa[3];
                ua[3] = pk_relu_bf16(cvt_pk_bf16(
                    __uint_as_float(w << 16) + c1.z,
                    __uint_as_float(w & 0xFFFF0000u) + c1.w));
            }
            {
                unsigned w = wb[0];
                ub[0] = pk_relu_bf16(cvt_pk_bf16(
                    __uint_as_float(w << 16) + c0.x,
                    __uint_as_float(w & 0xFFFF0000u) + c0.y));
                w = wb[1];
                ub[1] = pk_relu_bf16(cvt_pk_bf16(
                    __uint_as_float(w << 16) + c0.z,
                    __uint_as_float(w & 0xFFFF0000u) + c0.w));
                w = wb[2];
                ub[2] = pk_relu_bf16(cvt_pk_bf16(
                    __uint_as_float(w << 16) + c1.x,
                    __uint_as_float(w & 0xFFFF0000u) + c1.y));
                w = wb[3];
                ub[3] = pk_relu_bf16(cvt_pk_bf16(
                    __uint_as_float(w << 16) + c1.z,
                    __uint_as_float(w & 0xFFFF0000u) + c1.w));
            }
            afA[kt] = __builtin_bit_cast(short8v, ua);
            afB[kt] = __builtin_bit_cast(short8v, ub);
        }

        float part[2][4];
#pragma unroll
        for (int c = 0; c < 2; ++c)
#pragma unroll
            for (int j = 0; j < 4; ++j) part[c][j] = 0.f;

#pragma unroll
        for (int nh = 0; nh < 2; ++nh) {
            float4v accA[4], accB[4];
            float wv[4];
#pragma unroll
            for (int n = 0; n < 4; ++n) {
                int colg = (nh * 4 + n) * 16 + l15;
                float bv = b1s[colg];
                wv[n] = w2s[colg];
                accA[n] = (float4v){bv, bv, bv, bv};
                accB[n] = (float4v){bv, bv, bv, bv};
            }
            __builtin_amdgcn_s_setprio(1);
#pragma unroll
            for (int kt = 0; kt < 4; ++kt) {
#pragma unroll
                for (int n = 0; n < 4; ++n) {
                    short8v b = Bs[(kt * 8 + nh * 4 + n) * 64 + lane];
                    accA[n] = __builtin_amdgcn_mfma_f32_16x16x32_bf16(afA[kt], b, accA[n], 0, 0, 0);
                    accB[n] = __builtin_amdgcn_mfma_f32_16x16x32_bf16(afB[kt], b, accB[n], 0, 0, 0);
                }
            }
            __builtin_amdgcn_s_setprio(0);
#pragma unroll
            for (int n = 0; n < 4; ++n)
#pragma unroll
                for (int j = 0; j < 4; ++j) {
                    part[0][j] += fmaxf(accA[n][j], 0.f) * wv[n];
                    part[1][j] += fmaxf(accB[n][j], 0.f) * wv[n];
                }
        }

#pragma unroll
        for (int c = 0; c < 2; ++c)
#pragma unroll
            for (int j = 0; j < 4; ++j)
                part[c][j] = dpp_red16(part[c][j]);

        if (l15 == 0) {
            int ca = cell0 + s * 2;
            float4 pa = make_float4(part[0][0], part[0][1], part[0][2], part[0][3]);
            float4 pb = make_float4(part[1][0], part[1][1], part[1][2], part[1][3]);
            *(float4*)(pred + (size_t)ca * 16 + g * 4) = pa;
            *(float4*)(pred + (size_t)(ca + 1) * 16 + g * 4) = pb;
        }
    }
}

// ---------- ensemble pass: per pixel gather 4 preds + areas + combine ----------
__global__ __launch_bounds__(256) void k_ens(
    const float* __restrict__ pred, const float* __restrict__ b2g,
    float* __restrict__ out) {
    int p = blockIdx.x * 256 + threadIdx.x;   // 0..262143
    int qy = p >> 9, qx = p & 511;
    float bb = b2g[0];
    float pr[4], ar[4];
#pragma unroll
    for (int br = 0; br < 4; ++br) {
        int iy = min(max((qy + ((br & 2) ? 1 : -1)) >> 1, 0), 255);
        int ix = min(max((qx + ((br & 1) ? 1 : -1)) >> 1, 0), 255);
        int cy = qy - 2 * iy + 1, cx = qx - 2 * ix + 1;
        pr[br] = pred[((size_t)(iy * 256 + ix) * 16) + cy * 4 + cx] + bb;
        float ry = (float)(qy - 2 * iy) - 0.5f;
        float rx = (float)(qx - 2 * ix) - 0.5f;
        ar[br] = fabsf(ry * rx) + 1e-9f;
    }
    out[p] = (pr[0] * ar[3] + pr[1] * ar[2] + pr[2] * ar[1] + pr[3] * ar[0])
           / (ar[0] + ar[1] + ar[2] + ar[3]);
}

// ---------- host launcher ----------
extern "C" void kernel_launch(void* const* d_in, const int* in_sizes, int n_in,
                              void* d_out, int out_size, void* d_ws, size_t ws_size,
                              hipStream_t stream) {
    const float* feats2 = (const float*)d_in[0];
    const float* feats4 = (const float*)d_in[1];
    const float* feats32 = (const float*)d_in[2];
    const float* w2 = (const float*)d_in[4];
    const float* s2 = (const float*)d_in[5];
    const float* b2 = (const float*)d_in[6];
    const float* w4 = (const float*)d_in[7];
    const float* s4 = (const float*)d_in[8];
    const float* b4 = (const float*)d_in[9];
    const float* w32 = (const float*)d_in[10];
    const float* s32 = (const float*)d_in[11];
    const float* b32 = (const float*)d_in[12];
    const float* wf = (const float*)d_in[13];
    const float* sf = (const float*)d_in[14];
    const float* bf = (const float*)d_in[15];
    const float* mw0 = (const float*)d_in[16];
    const float* mb0 = (const float*)d_in[17];
    const float* mw1 = (const float*)d_in[18];
    const float* mb1 = (const float*)d_in[19];
    const float* mw2 = (const float*)d_in[20];
    const float* mb2 = (const float*)d_in[21];

    float* a4buf = (float*)d_ws;                          // 128*128*32 f32
    float* a32buf = a4buf + 524288;                       // 16*16*32 f32
    unsigned short* catb16 = (unsigned short*)(a32buf + 8192);   // 65536*96 bf16
    unsigned short* Gbuf = catb16 + 6291456;                     // 65536*128 bf16
    short* w1p = (short*)(Gbuf + 8388608);                // 16384 bf16
    short* w0fp = w1p + 16384;                            // 12288 bf16
    short* wfp = w0fp + 12288;                            // 82944 bf16
    float* corrbuf = (float*)(wfp + 82944);               // 16*128 f32
    float* predbuf = corrbuf + 2048;                      // 65536*16 f32 (4MB)
    short* w2fp = (short*)(predbuf + 1048576);            // 2048 bf16

    k_prep<<<2532, 256, 0, stream>>>(mw0, mw1, wf, mb0, w2,
                                     feats4, w4, s4, b4,
                                     feats32, w32, s32, b32,
                                     w1p, w0fp, wfp, corrbuf, w2fp,
                                     a4buf, a32buf);
    k_cat2<<<1024, 256, 0, stream>>>(feats2, w2fp, s2, b2, a4buf, a32buf, catb16);
    k_fuseG<<<1024, 256, 0, stream>>>(catb16, wfp, sf, bf, w0fp, Gbuf);
    k_mlpC<<<2048, 512, 0, stream>>>(Gbuf, corrbuf, w1p, mb1, mw2, predbuf);
    k_ens<<<1024, 256, 0, stream>>>(predbuf, mb2, (float*)d_out);
}